// Round 17
// baseline (2612.389 us; speedup 1.0000x reference)
//
#include <hip/hip_runtime.h>
#include <hip/hip_bf16.h>
#include <stdint.h>

// TiedEmbeddingLinear: out[8192, 32768] = x[8192,4096] . W^T
// Pass 1: dequant NF4 W -> bf16 (ws). Pass 2: x fp32 -> bf16 (ws).
// Pass 3: 256x256 bf16 NT-GEMM. R17 = R16's A-LDS/B-vmem split (respects the
// 15-deep lgkmcnt window) with IN-PLACE rolling for BOTH operand reg sets:
// af[8][2] (64 VGPR) pairs reissued after last use (np=1 chunks), bf[4][2]
// (32 VGPR) halves reissued after last use (end of each np sweep). Total
// ~116 VGPR + 128 AGPR acc — fits (512,2)'s 256-reg budget. R16's NaN was
// spill: af+bfP+bfQ+acc ~280 regs; spilling an async-written asm register
// saves garbage to scratch. 2D chunks (4 m-pairs x 2 n-pairs); LGKM gates
// retire full-tile-old reads (free); 3x VMCNT(8)/tile retire >=3/4-tile-old
// batches (free); one barrier/tile.

#define M_DIM 8192
#define N_DIM 32768
#define K_DIM 4096
#define NT    64        // K / BK, BK = 64

typedef __attribute__((ext_vector_type(8))) short short8;
typedef __attribute__((ext_vector_type(4))) float f32x4;

__device__ __forceinline__ ushort f2bf(float f) {
    union { __hip_bfloat16 b; ushort u; } cv;
    cv.b = __float2bfloat16(f);
    return cv.u;
}

__device__ __forceinline__ void gload16(const ushort* g, ushort* l) {
    __builtin_amdgcn_global_load_lds(
        (const __attribute__((address_space(1))) unsigned int*)g,
        (__attribute__((address_space(3))) unsigned int*)l,
        16, 0, 0);
}

// asm LDS read (opaque to alias analysis; we own lgkmcnt)
__device__ __forceinline__ short8 ldsread128(const ushort* p) {
    short8 r;
    uint32_t a = (uint32_t)(uintptr_t)(const __attribute__((address_space(3))) ushort*)p;
    asm volatile("ds_read_b128 %0, %1" : "=v"(r) : "v"(a));
    return r;
}

// asm global read into regs (B fragments, vmcnt domain); "memory" pins
// program order vs gload_lds/waitcnt so the vm FIFO ledger is exact.
__device__ __forceinline__ short8 gread128(const ushort* p) {
    short8 r;
    asm volatile("global_load_dwordx4 %0, %1, off" : "=v"(r) : "v"(p) : "memory");
    return r;
}

#define BAR()     asm volatile("s_barrier" ::: "memory")
#define VMCNT(N)  do { asm volatile("s_waitcnt vmcnt(" #N ")" ::: "memory"); \
                       __builtin_amdgcn_sched_barrier(0); } while (0)
#define LGKM(N)   do { asm volatile("s_waitcnt lgkmcnt(" #N ")" ::: "memory"); \
                       __builtin_amdgcn_sched_barrier(0); } while (0)

// ---------------- pass 1: dequant W ----------------
__global__ __launch_bounds__(256) void dequant_w(
    const int* __restrict__ qw, const float* __restrict__ cb,
    uint32_t* __restrict__ wout)
{
    __shared__ uint32_t lut[256];
    const int tid = threadIdx.x;
    {
        const uint32_t h = f2bf(cb[(tid >> 4) & 15]);   // high nibble -> even d
        const uint32_t l = f2bf(cb[tid & 15]);          // low nibble  -> odd d
        lut[tid] = h | (l << 16);
    }
    __syncthreads();

    const size_t base = (size_t)blockIdx.x * 256 + tid;
    const int4* q4 = (const int4*)qw;
    uint4* w4 = (uint4*)wout;
    #pragma unroll
    for (int it = 0; it < 16; ++it) {
        const size_t idx = base + (size_t)it * (4096 * 256);
        const int4 q = q4[idx];
        uint4 w;
        w.x = lut[q.x & 255]; w.y = lut[q.y & 255];
        w.z = lut[q.z & 255]; w.w = lut[q.w & 255];
        w4[idx] = w;
    }
}

// ---------------- pass 2: x fp32 -> bf16 ----------------
__global__ __launch_bounds__(256) void conv_x(
    const float* __restrict__ x, ushort* __restrict__ xb)
{
    const size_t base = (size_t)blockIdx.x * 256 + threadIdx.x;
    #pragma unroll
    for (int it = 0; it < 8; ++it) {
        const size_t idx = (base + (size_t)it * (2048 * 256)) * 8;
        const float4 a = *(const float4*)(x + idx);
        const float4 b = *(const float4*)(x + idx + 4);
        short8 o;
        o[0] = f2bf(a.x); o[1] = f2bf(a.y); o[2] = f2bf(a.z); o[3] = f2bf(a.w);
        o[4] = f2bf(b.x); o[5] = f2bf(b.y); o[6] = f2bf(b.z); o[7] = f2bf(b.w);
        *(short8*)(xb + idx) = o;
    }
}

// ---------------- pass 3: 256^2 bf16 NT-GEMM, all-in-place pipeline ---------
__global__ __launch_bounds__(512, 2) void gemm_p7(
    const ushort* __restrict__ xb, const ushort* __restrict__ wb,
    const float* __restrict__ absmax, float* __restrict__ out)
{
    __shared__ ushort smA[3 * 16384];   // 96 KiB: A 3-deep, [256 rows][64 bf16]

    const int tid  = threadIdx.x;
    const int lane = tid & 63;
    const int wv   = tid >> 6;      // 0..7
    const int wm   = wv >> 2;       // 0..1  (128-row block)
    const int wn   = wv & 3;        // 0..3  (64-col block)

    const int bid = blockIdx.x;
    const int gm0 = (bid & 31) << 8;    // m fast: B panels shared, A L3-resident
    const int gn0 = (bid >> 5) << 8;

    // staging (R8 exact): lane -> (row l8, swizzled source granule)
    const int l8    = lane >> 3;
    const int sgran = (lane & 7) ^ l8;

    const ushort* aSrc = xb + (size_t)(gm0 + wv * 16 + l8) * K_DIM + sgran * 8;

    const int lr  = lane & 15;
    const int g   = lane >> 4;
    const int lr7 = lane & 7;

    // per-lane B base: row = gn0 + wn*64 + lr, k-granule g
    const ushort* bgl = wb + (size_t)(gn0 + wn * 64 + lr) * K_DIM + g * 8;

    f32x4  acc[8][4] = {};
    short8 af[8][2];    // 64 VGPR: m-pairs reissued in place (np=1)
    short8 bf[4][2];    // 32 VGPR: n-halves reissued in place (per np sweep)

    #define LDF(P, ROW, S) \
        ldsread128((P) + ((ROW) + lr) * 64 + ((((S) * 4 + g) ^ lr7) * 8))

    #define STAGE_T(DSTBASE, KT) do { \
        gload16(aSrc + (size_t)(KT) * 64,                       (ushort*)smA + (DSTBASE) + wv * 1024); \
        gload16(aSrc + (size_t)(KT) * 64 + (size_t)8 * K_DIM,   (ushort*)smA + (DSTBASE) + wv * 1024 + 512); \
        gload16(aSrc + (size_t)(KT) * 64 + (size_t)128 * K_DIM, (ushort*)smA + (DSTBASE) + 8192 + wv * 1024); \
        gload16(aSrc + (size_t)(KT) * 64 + (size_t)136 * K_DIM, (ushort*)smA + (DSTBASE) + 8192 + wv * 1024 + 512); \
    } while (0)

    // chunk: af pair MP x bf half NP x 2 slices = 8 MFMA
    #define MFC2(MP, NP) do { \
        __builtin_amdgcn_s_setprio(1); \
        _Pragma("unroll") \
        for (int s = 0; s < 2; ++s) \
            _Pragma("unroll") \
            for (int m2 = 0; m2 < 2; ++m2) \
                _Pragma("unroll") \
                for (int n2 = 0; n2 < 2; ++n2) \
                    acc[2 * (MP) + m2][2 * (NP) + n2] = \
                        __builtin_amdgcn_mfma_f32_16x16x32_bf16( \
                            af[2 * (MP) + m2][s], bf[2 * (NP) + n2][s], \
                            acc[2 * (MP) + m2][2 * (NP) + n2], 0, 0, 0); \
        __builtin_amdgcn_s_setprio(0); \
    } while (0)

    // reissue af pair K from a1 = A(j+1) (staged tile j-1, barrier-retired)
    #define RD_P(K) do { \
        const ushort* _An = (const ushort*)smA + a1; \
        af[2 * (K)][0]     = LDF(_An, wm * 128 + (2 * (K)) * 16,     0); \
        af[2 * (K)][1]     = LDF(_An, wm * 128 + (2 * (K)) * 16,     1); \
        af[2 * (K) + 1][0] = LDF(_An, wm * 128 + (2 * (K) + 1) * 16, 0); \
        af[2 * (K) + 1][1] = LDF(_An, wm * 128 + (2 * (K) + 1) * 16, 1); \
    } while (0)

    // reissue bf half NP from globals of K-tile KT (4 vm ops)
    #define RD_BF(NP, KT) do { \
        const ushort* _bk = bgl + (size_t)(KT) * 64; \
        bf[2 * (NP)][0]     = gread128(_bk + (size_t)(2 * (NP)) * 16 * K_DIM); \
        bf[2 * (NP)][1]     = gread128(_bk + (size_t)(2 * (NP)) * 16 * K_DIM + 32); \
        bf[2 * (NP) + 1][0] = gread128(_bk + (size_t)(2 * (NP) + 1) * 16 * K_DIM); \
        bf[2 * (NP) + 1][1] = gread128(_bk + (size_t)(2 * (NP) + 1) * 16 * K_DIM + 32); \
    } while (0)

    // Tile j invariants. Entry: ds FIFO [af(j) 16, issued tile j-1 np=1];
    // vm FIFO [bf_lo(j) 4, bf_hi(j) 4]; bf regs hold j's values after gates.
    // Body:
    //   stage A(j+2) -> a2 (vm 4)            FIFO [bfL, bfH, stg] 12
    //   VMCNT(8): bf_lo(j) landed
    //   np=0: LGKM(12/8/4/0) -> MFC2(mp,0)   (each retires 1-tile-old af pair)
    //   RD_BF(0, j+1)                        FIFO [bfH, stg, bfL'] 12
    //   VMCNT(8): bf_hi(j) landed
    //   np=1: MFC2(mp,1); RD_P(mp)           (af(j+1) reads, no gates)
    //   RD_BF(1, j+1)                        FIFO [stg, bfL', bfH'] 12
    //   VMCNT(8): stage A(j+2) landed (full-tile lead)
    //   BAR; rotate a0/a1/a2.
    // Exit: ds [af(j+1) 16]; vm [bf_lo(j+1), bf_hi(j+1)]. QED per R7 rule.
    #define TILE(J) do { \
        STAGE_T(a2, (((J) + 2) & (NT - 1))); \
        VMCNT(8); \
        LGKM(12);  MFC2(0, 0); \
        LGKM(8);   MFC2(1, 0); \
        LGKM(4);   MFC2(2, 0); \
        LGKM(0);   MFC2(3, 0); \
        RD_BF(0, (((J) + 1) & (NT - 1))); \
        VMCNT(8); \
        MFC2(0, 1);  RD_P(0); \
        MFC2(1, 1);  RD_P(1); \
        MFC2(2, 1);  RD_P(2); \
        MFC2(3, 1);  RD_P(3); \
        RD_BF(1, (((J) + 1) & (NT - 1))); \
        VMCNT(8); \
        BAR(); \
        int _t = a0; a0 = a1; a1 = a2; a2 = _t; \
    } while (0)

    int a0 = 0, a1 = 16384, a2 = 32768;   // bufs: A(j), A(j+1), A(j+2)

    // ---- prologue: establish tile-0 entry state exactly ----
    STAGE_T(0, 0);          // A(0) -> a0   (vm 4)
    STAGE_T(16384, 1);      // A(1) -> a1   (vm 4)
    RD_BF(0, 0);            // bf_lo(0)     (vm 4)
    RD_BF(1, 0);            // bf_hi(0)     (vm 4)
    VMCNT(8);               // retire both stages; bf(0) stays in flight
    BAR();
    #pragma unroll
    for (int m = 0; m < 8; ++m) {          // af(0): 16 ds reads, pair order
        af[m][0] = LDF((const ushort*)smA, wm * 128 + m * 16, 0);
        af[m][1] = LDF((const ushort*)smA, wm * 128 + m * 16, 1);
    }
    // ds FIFO [af(0) 16]; vm FIFO [bf_lo(0) 4, bf_hi(0) 4] — entry state.

    for (int j = 0; j < NT; ++j)
        TILE(j);

    LGKM(0);    // retire trailing af reads (dead wrap values)
    VMCNT(0);   // retire trailing bf/stage ops before regs are reused

    // ---- epilogue: absmax[col] scale, plain fp32 stores ----
    float am[4];
    #pragma unroll
    for (int n = 0; n < 4; ++n)
        am[n] = absmax[gn0 + wn * 64 + n * 16 + lr];

    const int row0 = gm0 + wm * 128 + g * 4;
    const int col0 = gn0 + wn * 64 + lr;
    #pragma unroll
    for (int m = 0; m < 8; ++m) {
        #pragma unroll
        for (int n = 0; n < 4; ++n) {
            #pragma unroll
            for (int r = 0; r < 4; ++r) {
                out[(size_t)(row0 + m * 16 + r) * N_DIM + col0 + n * 16] =
                    acc[m][n][r] * am[n];
            }
        }
    }
}

extern "C" void kernel_launch(void* const* d_in, const int* in_sizes, int n_in,
                              void* d_out, int out_size, void* d_ws, size_t ws_size,
                              hipStream_t stream) {
    const float* x      = (const float*)d_in[0];
    const int*   qw     = (const int*)d_in[1];
    const float* absmax = (const float*)d_in[2];
    const float* cb     = (const float*)d_in[3];
    float* out = (float*)d_out;

    const size_t W_BYTES = (size_t)N_DIM * K_DIM * 2;   // 256 MiB bf16 W
    uint32_t* wq  = (uint32_t*)d_ws;
    ushort*   xbf = (ushort*)((char*)d_ws + W_BYTES);

    dequant_w<<<4096, 256, 0, stream>>>(qw, cb, wq);
    conv_x<<<2048, 256, 0, stream>>>(x, xbf);
    gemm_p7<<<dim3((M_DIM / 256) * (N_DIM / 256)), dim3(512), 0, stream>>>(
        xbf, (const ushort*)wq, absmax, out);
}